// Round 7
// baseline (191.407 us; speedup 1.0000x reference)
//
#include <hip/hip_runtime.h>
#include <math.h>

#define B_GRAPHS 4096
#define NPG 64
#define E_DIM 128
#define INV_B (1.0f / 4096.0f)

static __device__ __forceinline__ float4 fmax4(float4 a, float4 b) {
    return make_float4(fmaxf(a.x, b.x), fmaxf(a.y, b.y),
                       fmaxf(a.z, b.z), fmaxf(a.w, b.w));
}

// ---------------------------------------------------------------------------
// Kernel A: pure gather + segment-max. grid (4096, 2 sides), 256 threads.
// One (graph, side) per block; 8 float4 gathers/thread; shfl_xor(32) +
// SoA scalar LDS partials (conflict-free) -> pooled[side][g][128].
// Small LDS (2.3 KB) -> high occupancy; no compute tail, so resident waves
// keep the L2-miss queue saturated (duty-cycle theory from round-1 evidence).
// ---------------------------------------------------------------------------
__global__ __launch_bounds__(256) void gather_pool_k(
    const int* __restrict__ lx, const int* __restrict__ rx,
    const float* __restrict__ emb, float* __restrict__ pooled)
{
    const int g    = blockIdx.x;
    const int side = blockIdx.y;
    const int t    = threadIdx.x;
    const int w    = t >> 6;
    const int lane = t & 63;

    __shared__ int   idx[NPG];
    __shared__ float red[4][E_DIM];   // SoA [component][w*32 + q]

    const int* __restrict__ x = side ? rx : lx;
    if (t < NPG) idx[t] = x[g * NPG + t];
    __syncthreads();

    const int n0 = t >> 5;   // node subgroup 0..7
    const int q  = t & 31;   // float4 slot within a 128-float row
    const float4* __restrict__ e4 = reinterpret_cast<const float4*>(emb);

    float4 a = make_float4(-INFINITY, -INFINITY, -INFINITY, -INFINITY);
    #pragma unroll
    for (int i = 0; i < 8; ++i)
        a = fmax4(a, e4[(size_t)idx[(i << 3) + n0] * 32 + q]);

    // lanes l and l+32 share q and hold adjacent n0 -> combine
    a.x = fmaxf(a.x, __shfl_xor(a.x, 32));
    a.y = fmaxf(a.y, __shfl_xor(a.y, 32));
    a.z = fmaxf(a.z, __shfl_xor(a.z, 32));
    a.w = fmaxf(a.w, __shfl_xor(a.w, 32));

    if (lane < 32) {                  // conflict-free: consecutive words
        const int o = w * 32 + lane;
        red[0][o] = a.x; red[1][o] = a.y; red[2][o] = a.z; red[3][o] = a.w;
    }
    __syncthreads();

    if (t < 32) {
        float4 m;
        m.x = fmaxf(fmaxf(red[0][t],      red[0][32 + t]),
                    fmaxf(red[0][64 + t], red[0][96 + t]));
        m.y = fmaxf(fmaxf(red[1][t],      red[1][32 + t]),
                    fmaxf(red[1][64 + t], red[1][96 + t]));
        m.z = fmaxf(fmaxf(red[2][t],      red[2][32 + t]),
                    fmaxf(red[2][64 + t], red[2][96 + t]));
        m.w = fmaxf(fmaxf(red[3][t],      red[3][32 + t]),
                    fmaxf(red[3][64 + t], red[3][96 + t]));
        reinterpret_cast<float4*>(pooled)[((size_t)side * B_GRAPHS + g) * 32 + t] = m;
    }
}

// ---------------------------------------------------------------------------
// Kernel B: matvec + cos + loss. grid 4096, 256 threads (side=t&1, e=t>>1).
// pooled (4 MB) and W (64 KB) are L2-resident; ~268 MB of L2 W-reads
// at 34.5 TB/s ~= 8 us floor. Tail identical to the measured-correct
// fused-kernel tail (pair shfl_xor exchange + full-wave reduce).
// ---------------------------------------------------------------------------
__global__ __launch_bounds__(256) void matvec_cos_k(
    const float* __restrict__ pooled, const float* __restrict__ W,
    const float* __restrict__ bias, const float* __restrict__ label,
    float* __restrict__ out)
{
    const int g    = blockIdx.x;
    const int t    = threadIdx.x;
    const int w    = t >> 6;
    const int lane = t & 63;

    __shared__ float4 P4[2][32];
    __shared__ float  wred[3][4];

    if (t < 64) {
        const int side = t >> 5;
        const int qq   = t & 31;
        P4[side][qq] = reinterpret_cast<const float4*>(pooled)
            [((size_t)side * B_GRAPHS + g) * 32 + qq];
    }
    __syncthreads();

    float acc;
    {
        const int side = t & 1;
        const int e    = t >> 1;
        acc = bias[e];
        const float4* __restrict__ wr =
            reinterpret_cast<const float4*>(W) + (size_t)e * 32;
        const float4* __restrict__ pv = P4[side];
        #pragma unroll 8
        for (int fi = 0; fi < 32; ++fi) {
            const float4 wv = wr[fi];
            const float4 p  = pv[fi];
            acc = fmaf(p.x, wv.x, acc);
            acc = fmaf(p.y, wv.y, acc);
            acc = fmaf(p.z, wv.z, acc);
            acc = fmaf(p.w, wv.w, acc);
        }
    }

    {
        const float other = __shfl_xor(acc, 1);
        const float l = (t & 1) ? other : acc;
        const float r = (t & 1) ? acc   : other;
        float dot = l * r;
        float nl  = l * l;
        float nr  = r * r;
        #pragma unroll
        for (int off = 1; off < 64; off <<= 1) {
            dot += __shfl_xor(dot, off);
            nl  += __shfl_xor(nl,  off);
            nr  += __shfl_xor(nr,  off);
        }
        if (lane == 0) {   // wave sum counts each e twice -> halve later
            wred[0][w] = dot; wred[1][w] = nl; wred[2][w] = nr;
        }
    }
    __syncthreads();

    if (t == 0) {
        const float dd = 0.5f * (wred[0][0] + wred[0][1] + wred[0][2] + wred[0][3]);
        const float ll = 0.5f * (wred[1][0] + wred[1][1] + wred[1][2] + wred[1][3]);
        const float rr = 0.5f * (wred[2][0] + wred[2][1] + wred[2][2] + wred[2][3]);
        const float nlv = fmaxf(sqrtf(ll), 1e-6f);
        const float nrv = fmaxf(sqrtf(rr), 1e-6f);
        const float c   = dd / (nlv * nrv);
        out[1 + g] = c;
        const float lab  = label[g];
        const float mm   = fmaxf(1.0f - c, 0.0f);
        const float loss = 0.5f * ((1.0f - lab) * c * c + lab * mm * mm);
        atomicAdd(out, loss * INV_B);
    }
}

// ---------------------------------------------------------------------------
// Inputs (setup_inputs order):
// 0 left_x (N int32), 1 left_graph_index (B), 2 right_x (N), 3 right_graph_index,
// 4 left_x_batch (N), 5 right_x_batch (N), 6 label (B f32),
// 7 emb_table (V*E f32), 8 W (E*E f32), 9 b (E f32)
// Output: [0] = sim_loss, [1..B] = cos  (float32, out_size = B+1)
// ---------------------------------------------------------------------------
extern "C" void kernel_launch(void* const* d_in, const int* in_sizes, int n_in,
                              void* d_out, int out_size, void* d_ws, size_t ws_size,
                              hipStream_t stream)
{
    const int*   lx    = (const int*)d_in[0];
    const int*   rx    = (const int*)d_in[2];
    const float* label = (const float*)d_in[6];
    const float* emb   = (const float*)d_in[7];
    const float* W     = (const float*)d_in[8];
    const float* bias  = (const float*)d_in[9];

    float* out    = (float*)d_out;   // [0]=loss (atomic-accumulated), [1..B]=cos
    float* pooled = (float*)d_ws;    // [2][B_GRAPHS][E_DIM] = 4 MB

    hipMemsetAsync(out, 0, sizeof(float), stream);

    dim3 gA(B_GRAPHS, 2);
    gather_pool_k<<<gA, 256, 0, stream>>>(lx, rx, emb, pooled);
    matvec_cos_k<<<B_GRAPHS, 256, 0, stream>>>(pooled, W, bias, label, out);
}